// Round 13
// baseline (261.023 us; speedup 1.0000x reference)
//
#include <hip/hip_runtime.h>
#include <stdint.h>

// LSTM fused: B=8192, T=128, I=32, H=64, OUT=8. fp32 internal state, bf16 MFMA.
// R19 = R18 (122.8us, LDS 13.8K) with ONE sync-structure change: the
// per-step __syncthreads() is replaced by an lgkm-only barrier
//   asm("s_waitcnt lgkmcnt(0)" ::: "memory"); s_barrier; asm("" ::: "memory");
// (T4: never drain vmcnt in the main loop). R18 post-mortem: __syncthreads
// drains vmcnt(0) too, so every step's barrier waited ~500cy on the x
// prefetch (fresh HBM load, ~900cy) whose result is only needed NEXT step —
// this cancelled the staging-deletion savings (R18 neutral vs R17 despite
// -41KB LDS and -1.6M conflicts). Cross-wave visibility in the step loop is
// LDS-only (h writes/reads): lgkmcnt(0)+s_barrier is sufficient (LDS has no
// caches); the x load is thread-private and gets its compiler-inserted
// vmcnt wait at first use (next step's accx MFMA), ~2300cy after issue —
// HBM latency fully covered. Init/epilogue keep full __syncthreads().
// R18 ledger: x streams global->reg 1-step-deep; xbuf deleted. R17: setprio
// through gates+writes, unroll 4. R16 (REVERTED): packed write serialized
// the tail — per-r incremental h-writes are load-bearing. Parallelism ledger
// (closed): 2048 waves = exactly 2/SIMD (R9/R12/R13 all worse). R15:
// {reg-carried x-frag, accx at step top, cst in 2log2e domain}; R14: {exp2
// scale folded into W/bias}; R11: {loads hoisted, dependent MFMAs off the
// lgkm wait}; R10: bank conflicts off-path, HPAD=144 known-good.
// NaN ledger: R1/R5/R7 (vector WEIGHT loads, plain body) and R6 (K=16 f16)
// all NaN'd; R2/R3/R8/R11/R14/R15/R17/R18 (scalar weight loads + sniff
// dispatcher) passed. Do not reintroduce without isolated A/B.

#define T_STEPS 128
#define ISZ 32
#define HSZ 64
#define B_TOT 8192
#define B_TILE 16
#define HPAD 144

typedef short bf16x8 __attribute__((ext_vector_type(8)));
typedef float f32x4 __attribute__((ext_vector_type(4)));

#define LOG2E 1.44269504088896340736f

// lgkm-only barrier: drain own LDS ops, sync, fence. Does NOT drain vmcnt —
// in-flight global loads (thread-private x prefetch) stay in flight.
#define LGKM_BARRIER() do {                                    \
    asm volatile("s_waitcnt lgkmcnt(0)" ::: "memory");         \
    __builtin_amdgcn_s_barrier();                              \
    asm volatile("" ::: "memory");                             \
} while (0)

__device__ __forceinline__ float bf2f(unsigned short s) {
    union { unsigned int u; float f; } v; v.u = ((unsigned int)s) << 16; return v.f;
}
__device__ __forceinline__ unsigned short f2bf(float f) {
    union { float f; unsigned int u; } v; v.f = f;
    unsigned int u = v.u;
    return (unsigned short)((u + 0x7fffu + ((u >> 16) & 1u)) >> 16);  // RNE
}
// prescaled-gate helpers: z already carries the exp2 scale (folded into W).
// sig_pre: z = -LOG2E*x -> sigmoid(x). z->+inf: exp2->inf, rcp->0. Safe.
__device__ __forceinline__ float sig_pre(float z) {
    return __builtin_amdgcn_rcpf(1.0f + __builtin_amdgcn_exp2f(z));
}

template <bool F32>
__device__ __forceinline__ float ldin(const void* p, size_t i) {
    if (F32) return ((const float*)p)[i];
    return bf2f(((const unsigned short*)p)[i]);
}

template <bool F32>
__device__ __forceinline__ void run_body(
    const void* xv, const void* Wihv, const void* Whhv, const void* bihv,
    const void* bhhv, const void* Wfcv, const void* bfcv, void* outv,
    unsigned short (&hbuf)[2][B_TILE][HPAD],
    float (&hfin)[B_TILE][HSZ + 4])
{
    const int tid  = threadIdx.x;
    const int wid  = tid >> 6;
    const int lane = tid & 63;
    const int q    = lane >> 4;   // A/B frag k-quad; C/D row-quad
    const int tn   = lane & 15;   // A: batch row m; B/C: unit col n
    const int u    = wid * 16 + tn;
    const int b0   = blockIdx.x * B_TILE;

    // B-operand weight frags, loaded once (scalar loads — see NaN ledger).
    // Exp2 scale folded in: i/f/o rows x (-LOG2E), g rows x (+2*LOG2E),
    // applied in fp32 BEFORE the single bf16 rounding (same error profile).
    bf16x8 wf[4][3];
    f32x4 biasC[4];   // bias broadcast into a C-operand vector: no acc-init movs
    #pragma unroll
    for (int g = 0; g < 4; ++g) {
        const float sc = (g == 2) ? (2.0f * LOG2E) : (-LOG2E);
        const int row = g * HSZ + u;
        #pragma unroll
        for (int j = 0; j < 8; ++j) {
            wf[g][0][j] = (short)f2bf(sc * ldin<F32>(Whhv, row * HSZ + q * 8 + j));
            wf[g][1][j] = (short)f2bf(sc * ldin<F32>(Whhv, row * HSZ + 32 + q * 8 + j));
            wf[g][2][j] = (short)f2bf(sc * ldin<F32>(Wihv, row * ISZ + q * 8 + j));
        }
        const float b = sc * (ldin<F32>(bihv, row) + ldin<F32>(bhhv, row));
        #pragma unroll
        for (int e = 0; e < 4; ++e) biasC[g][e] = b;
    }

    // per-lane x frag base (element offset): x[b0+tn][t][q*8 .. q*8+7].
    // 16B-aligned for bf16 (base 64B-mult + q*16B), 32B-aligned for f32.
    const size_t xbase = ((size_t)(b0 + tn) * T_STEPS) * ISZ + q * 8;

    // x register pipeline: pend* holds the (issued) frag for the NEXT step.
    // Compiler inserts the vmcnt wait at first use (accx MFMA) — one full
    // step-wall after issue, so HBM latency is covered without barrier drains.
    bf16x8 pendb;
    f32x4  pend0, pend1;
    if (F32) {
        const float* xf = (const float*)xv + xbase;
        pend0 = *(const f32x4*)(xf);
        pend1 = *(const f32x4*)(xf + 4);
    } else {
        pendb = *(const bf16x8*)((const unsigned short*)xv + xbase);
    }

    // h(0) = 0
    for (int i = tid; i < 2 * B_TILE * HPAD; i += 256) ((unsigned short*)hbuf)[i] = 0;
    __syncthreads();  // init barrier: full drain is fine (once)

    // c-state kept in the 2*log2e domain (cstS = 2*LOG2E * c).
    float cstS[4] = {0.f, 0.f, 0.f, 0.f};
    float hl[4]   = {0.f, 0.f, 0.f, 0.f};

    #pragma unroll 4
    for (int t = 0; t < T_STEPS; ++t) {
        const int rb = t & 1, wb = rb ^ 1;
        // issue h A-frag ds_reads FIRST (longest pole; latency covered by
        // the accx MFMAs below — R11/R15 ledger).
        const bf16x8 a0 = *(const bf16x8*)&hbuf[rb][tn][q * 8];       // h k0..31
        const bf16x8 a1 = *(const bf16x8*)&hbuf[rb][tn][32 + q * 8];  // h k32..63

        // materialize this step's x frag from the pending regs, then issue
        // next step's load (stays in flight across the lgkm-only barrier).
        bf16x8 axc;
        if (F32) {
            #pragma unroll
            for (int j = 0; j < 4; ++j) {
                axc[j]     = (short)f2bf(pend0[j]);
                axc[4 + j] = (short)f2bf(pend1[j]);
            }
        } else {
            axc = pendb;
        }
        const int t1 = (t < T_STEPS - 1) ? t + 1 : t;  // clamp: last re-load harmless
        if (F32) {
            const float* xf = (const float*)xv + xbase + (size_t)t1 * ISZ;
            pend0 = *(const f32x4*)(xf);
            pend1 = *(const f32x4*)(xf + 4);
        } else {
            pendb = *(const bf16x8*)((const unsigned short*)xv + xbase + (size_t)t1 * ISZ);
        }

        __builtin_amdgcn_s_setprio(1);
        // x-contribution FIRST, from registers: its issue+pipe latency
        // covers part of a0/a1's ds_read latency.
        f32x4 acc[4];
        #pragma unroll
        for (int g = 0; g < 4; ++g)
            acc[g] = __builtin_amdgcn_mfma_f32_16x16x32_bf16(axc, wf[g][2], biasC[g], 0, 0, 0);
        #pragma unroll
        for (int g = 0; g < 4; ++g)
            acc[g] = __builtin_amdgcn_mfma_f32_16x16x32_bf16(a0, wf[g][0], acc[g], 0, 0, 0);
        #pragma unroll
        for (int g = 0; g < 4; ++g)
            acc[g] = __builtin_amdgcn_mfma_f32_16x16x32_bf16(a1, wf[g][1], acc[g], 0, 0, 0);

        // gate trans phase (still prio 1). exp2 args come straight from the
        // MFMA output (scale pre-folded into W). cstS in 2*log2e domain.
        #pragma unroll
        for (int r = 0; r < 4; ++r) {
            const float gi  = sig_pre(acc[0][r]);
            const float gf  = sig_pre(acc[1][r]);
            const float rg  = __builtin_amdgcn_rcpf(1.0f + __builtin_amdgcn_exp2f(acc[2][r]));
            const float ggS = __builtin_fmaf(rg, -4.0f * LOG2E, 2.0f * LOG2E);  // 2L*tanh
            const float go  = sig_pre(acc[3][r]);
            cstS[r] = gf * cstS[r] + gi * ggS;
            const float th = 1.0f - 2.0f * __builtin_amdgcn_rcpf(1.0f + __builtin_amdgcn_exp2f(cstS[r]));
            const float hv = go * th;
            hl[r] = hv;
            const int m = q * 4 + r;  // C/D row = batch
            hbuf[wb][m][u] = f2bf(hv);  // per-r incremental write (ledger)
        }
        __builtin_amdgcn_s_setprio(0);

        // lgkm-only barrier: h writes drained + synced; x prefetch UNTOUCHED.
        LGKM_BARRIER();
    }

    // epilogue: out[b][j] = h_T(fp32) . Wfc[j,:] + bfc[j]
    #pragma unroll
    for (int r = 0; r < 4; ++r) hfin[q * 4 + r][u] = hl[r];
    __syncthreads();
    if (tid < B_TILE * 8) {
        const int m = tid >> 3, j = tid & 7;
        float s = ldin<F32>(bfcv, j);
        #pragma unroll
        for (int k = 0; k < HSZ; ++k) s += hfin[m][k] * ldin<F32>(Wfcv, j * HSZ + k);
        const size_t o = (size_t)(b0 + m) * 8 + j;
        if (F32) ((float*)outv)[o] = s;
        else     ((unsigned short*)outv)[o] = f2bf(s);
    }
}

__global__ __launch_bounds__(256, 2) void lstm_fused(
    const void* __restrict__ x, const void* __restrict__ Wih,
    const void* __restrict__ Whh, const void* __restrict__ bih,
    const void* __restrict__ bhh, const void* __restrict__ Wfc,
    const void* __restrict__ bfc, void* __restrict__ out)
{
    __shared__ unsigned short hbuf[2][B_TILE][HPAD];
    __shared__ float hfin[B_TILE][HSZ + 4];

    // dtype sniff (guard): fp32 data read as uint16 halves has mantissa-garbage
    // halves decoding to huge-exponent bf16s; real bf16 data never exceeds 2^17.
    const unsigned short* xu = (const unsigned short*)x;
    const int lane = threadIdx.x & 63;
    const unsigned short s0 = xu[lane * 2];
    const unsigned short s1 = xu[lane * 2 + 1];
    const int big = (((s0 >> 7) & 0xFF) >= 0x90) || (((s1 >> 7) & 0xFF) >= 0x90);
    const bool isf32 = __any(big) != 0;

    if (isf32) run_body<true >(x, Wih, Whh, bih, bhh, Wfc, bfc, out, hbuf, hfin);
    else       run_body<false>(x, Wih, Whh, bih, bhh, Wfc, bfc, out, hbuf, hfin);
}

extern "C" void kernel_launch(void* const* d_in, const int* in_sizes, int n_in,
                              void* d_out, int out_size, void* d_ws, size_t ws_size,
                              hipStream_t stream) {
    lstm_fused<<<dim3(B_TOT / B_TILE), dim3(256), 0, stream>>>(
        d_in[0], d_in[1], d_in[2], d_in[3], d_in[4], d_in[5], d_in[6], d_out);
}